// Round 7
// baseline (444.775 us; speedup 1.0000x reference)
//
#include <hip/hip_runtime.h>
#include <stdint.h>

#define BATCH  256
#define CDIM   2048
#define HW     49
#define NTOK   50
#define MROWS  (BATCH * NTOK)   // 12800
#define ODIM   1024
#define NHEADS 32

typedef __attribute__((ext_vector_type(8))) short short8;
typedef __attribute__((ext_vector_type(4))) float f32x4;
typedef unsigned short u16;
typedef unsigned int   u32;

__device__ __forceinline__ float bf2f(u16 u) {
  union { u32 i; float f; } v; v.i = ((u32)u) << 16; return v.f;
}
__device__ __forceinline__ u16 f2bf(float f) {
  union { float f; u32 i; } v; v.f = f;
  u32 r = v.i + 0x7fffu + ((v.i >> 16) & 1u);   // round-to-nearest-even
  return (u16)(r >> 16);
}

// async global->LDS, 16 bytes per lane (wave-uniform base + lane*16 dest)
__device__ __forceinline__ void async16(const void* g, void* l) {
  __builtin_amdgcn_global_load_lds(
      (const __attribute__((address_space(1))) u32*)g,
      (__attribute__((address_space(3))) u32*)l, 16, 0, 0);
}

// barrier that is ALSO a compiler memory fence (R5 lesson: the plain builtin
// s_barrier is NOT a fence -> compiler hoisted a global_load_lds above it,
// racing a slower wave's in-flight ds_reads of the same LDS region).
#define BARRIER() asm volatile("s_barrier" ::: "memory")

// ---------------- fp32 -> bf16 weight convert (both weights, one launch) ----
__global__ __launch_bounds__(256) void cvt2_kernel(const float* __restrict__ a,
                                                   u16* __restrict__ oa, int n4a,
                                                   const float* __restrict__ bsrc,
                                                   u16* __restrict__ ob, int n4b) {
  int i = blockIdx.x * 256 + threadIdx.x;
  const float* src; u16* dst; int idx;
  if (i < n4a) { src = a; dst = oa; idx = i; }
  else {
    idx = i - n4a;
    if (idx >= n4b) return;
    src = bsrc; dst = ob;
  }
  float4 v = reinterpret_cast<const float4*>(src)[idx];
  ushort4 o;
  o.x = f2bf(v.x); o.y = f2bf(v.y); o.z = f2bf(v.z); o.w = f2bf(v.w);
  reinterpret_cast<ushort4*>(dst)[idx] = o;
}

// ---------------- token prep: x[B,C,49] -> T[B*50, C] bf16 ----------------
__global__ __launch_bounds__(256) void prep_kernel(const float* __restrict__ x,
                                                   const float* __restrict__ pos,
                                                   u16* __restrict__ T) {
  const int blk = blockIdx.x;
  const int b  = blk >> 5;             // 32 chunks of 64 channels
  const int c0 = (blk & 31) * 64;
  __shared__ float xs[64 * HW];
  __shared__ float mean[64];
  const float* src = x + ((size_t)b * CDIM + c0) * HW;  // 3136 floats
  for (int i = threadIdx.x; i < 64 * HW / 4; i += 256)
    reinterpret_cast<float4*>(xs)[i] = reinterpret_cast<const float4*>(src)[i];
  __syncthreads();
  if (threadIdx.x < 64) {
    float s = 0.f;
#pragma unroll
    for (int j = 0; j < HW; j++) s += xs[threadIdx.x * HW + j];
    mean[threadIdx.x] = s * (1.0f / 49.0f);
  }
  __syncthreads();
  for (int wi = threadIdx.x; wi < NTOK * 8; wi += 256) {
    const int n = wi >> 3;
    const int g = (wi & 7) * 8;
    alignas(16) u16 ov[8];
#pragma unroll
    for (int u = 0; u < 8; u++) {
      const int c = g + u;
      float val = (n == 0) ? mean[c] : xs[c * HW + (n - 1)];
      val += pos[n * CDIM + c0 + c];
      ov[u] = f2bf(val);
    }
    *reinterpret_cast<uint4*>(&T[((size_t)b * NTOK + n) * CDIM + c0 + g]) =
        *reinterpret_cast<const uint4*>(ov);
  }
}

// ---------------- 256x256 pipelined GEMM (B^T): C = A*Bm^T + bias ----------
// Cross-tile pre-read pipeline, counted lgkm, 2 asm-fenced barriers/tile.
// launch_bounds(512,1): LDS(128KB) caps at 1 block/CU anyway; lifting the
// 256-reg cap removes R4's scratch spill.
//
//   P0: STG A1,B1,B0(j+1) [other buf, 6 ld]; read b-hi(j); lgkm(4)
//       [drains the 12 pre-reads]; Q(lo,lo)=a0*BLO; BAR1
//   P1: read a-hi(j)->a1; lgkm(8) [drains b-hi]; Q(lo,hi)=a0*BHI
//   P2: lgkm(0) [drains a-hi]; Q(hi,hi)=a1*BHI
//   P3: STG A0(j+2) [cur buf]; vmcnt(2|0); BAR2;
//       pre-read a-lo(j+1)->a0, b-lo(j+1)->BHI [12 ld]; Q(hi,lo)=a1*BLO
//
// vmcnt(2)@P3: queue = A0(j+1)[(j-1).P3] + A1,B1,B0(j+1)[P0] + A0(j+2)[P3]
// = 10 -> drains all but A0(j+2) => tile j+1 fully landed before BAR2+preread.
// WAR ledger (region: last drain -> fenced barrier(s) -> overwrite issue):
//   a-lo(j) pre-reads drained lgkm(4)@P0 -> BAR1,2 phases -> STG A0(j+2)@P3
//   a-hi(j-1) drained lgkm(0)@(j-1).P2 -> BAR2(j-1) -> STG A1(j+1)@j.P0
//   b-hi(j-1) drained lgkm(8)@(j-1).P1 -> BAR2(j-1) -> STG B1(j+1)@j.P0
//   b-lo(j-1) drained lgkm(4)@(j-1).P0 -> BAR1,BAR2(j-1) -> STG B0(j+1)@j.P0
// All barriers are asm-fenced so no memory op crosses at compile time.
// b arrays swap roles per tile (b-lo(j+1) pre-read into dead BHI regs)
// -> 2x unroll, NK even.
template<int OUT_BF16>
__global__ __launch_bounds__(512, 1)
void gemm256(const u16* __restrict__ A, const u16* __restrict__ Bm,
             const float* __restrict__ bias, void* __restrict__ Cout,
             int M, int N, int K, int nbx) {
  __shared__ __align__(16) u16 smem[65536];   // 128 KiB

  const int NK = K >> 6;
  const int t = threadIdx.x;
  const int lane = t & 63;
  const int wid = t >> 6;
  const int wm = wid >> 2;          // 0..1
  const int wn = wid & 3;           // 0..3

  // bijective XCD swizzle (gridDim.x % 8 == 0)
  const int nwg = gridDim.x;
  const int cpx = nwg >> 3;
  const int orig = blockIdx.x;
  const int swz = (orig & 7) * cpx + (orig >> 3);
  const int bx = swz % nbx;
  const int by = swz / nbx;
  const int m0 = by * 256, n0 = bx * 256;

  // staging source (pre-swizzled octet so linear LDS dest = swizzled layout)
  const int tr  = t >> 3;
  const int to8 = ((t & 7) ^ (tr & 7)) << 3;
  const int t8  = t << 3;
  const u16* pA0 = A  + (size_t)(m0 + tr) * K + to8;
  const u16* pB0 = Bm + (size_t)(n0 + tr) * K + to8;

  // ds_read offsets (elements), granule g=kk*4+hi XORed with row&7
  const int lr = lane & 15, hi = lane >> 4;
  const int sx = lr & 7;
  const int aK0 = ((wm * 128 + lr) << 6) + (((0 + hi) ^ sx) << 3);
  const int aK1 = ((wm * 128 + lr) << 6) + (((4 + hi) ^ sx) << 3);
  const int bK0 = 16384 + ((wn * 64 + lr) << 6) + (((0 + hi) ^ sx) << 3);
  const int bK1 = 16384 + ((wn * 64 + lr) << 6) + (((4 + hi) ^ sx) << 3);

  f32x4 acc[8][4] = {};
  short8 a0[4][2], a1[4][2], bA[2][2], bB[2][2];

  auto STG = [&](int kti, int isB, int h) {
    if (kti < NK) {
      const u16* g = (isB ? pB0 : pA0) + (size_t)(h * 128) * K + kti * 64;
      u16* l = &smem[((kti & 1) << 15) + (isB << 14) + (h << 13) + t8];
      async16(g, l);
      async16(g + (size_t)64 * K, l + 4096);
    }
  };

#define MFMA4x2(M0, N0, AARR, BARR)                                           \
  _Pragma("unroll")                                                           \
  for (int fm = 0; fm < 4; ++fm) {                                            \
    _Pragma("unroll")                                                         \
    for (int fn = 0; fn < 2; ++fn) {                                          \
      acc[(M0) + fm][(N0) + fn] = __builtin_amdgcn_mfma_f32_16x16x32_bf16(    \
          AARR[fm][0], BARR[fn][0], acc[(M0) + fm][(N0) + fn], 0, 0, 0);      \
      acc[(M0) + fm][(N0) + fn] = __builtin_amdgcn_mfma_f32_16x16x32_bf16(    \
          AARR[fm][1], BARR[fn][1], acc[(M0) + fm][(N0) + fn], 0, 0, 0);      \
    }                                                                         \
  }

#define TILE(J, BLO, BHI)                                                     \
  {                                                                           \
    const u16* sa = &smem[((J) & 1) << 15];                                   \
    const u16* sn = &smem[(((J) + 1) & 1) << 15];                             \
    /* ---- P0: front-load tile j+1 staging except A0 ---- */                 \
    STG((J) + 1, 0, 1); STG((J) + 1, 1, 1); STG((J) + 1, 1, 0);               \
    BHI[0][0] = *(const short8*)&sa[bK0 + 2048];                              \
    BHI[0][1] = *(const short8*)&sa[bK1 + 2048];                              \
    BHI[1][0] = *(const short8*)&sa[bK0 + 3072];                              \
    BHI[1][1] = *(const short8*)&sa[bK1 + 3072];                              \
    asm volatile("s_waitcnt lgkmcnt(4)" ::: "memory");                        \
    __builtin_amdgcn_sched_barrier(0);                                        \
    __builtin_amdgcn_s_setprio(1);                                            \
    MFMA4x2(0, 0, a0, BLO);                                                   \
    __builtin_amdgcn_s_setprio(0);                                            \
    BARRIER();                                                                \
    /* ---- P1 ---- */                                                        \
    a1[0][0] = *(const short8*)&sa[aK0 + 4096];                               \
    a1[0][1] = *(const short8*)&sa[aK1 + 4096];                               \
    a1[1][0] = *(const short8*)&sa[aK0 + 5120];                               \
    a1[1][1] = *(const short8*)&sa[aK1 + 5120];                               \
    a1[2][0] = *(const short8*)&sa[aK0 + 6144];                               \
    a1[2][1] = *(const short8*)&sa[aK1 + 6144];                               \
    a1[3][0] = *(const short8*)&sa[aK0 + 7168];                               \
    a1[3][1] = *(const short8*)&sa[aK1 + 7168];                               \
    asm volatile("s_waitcnt lgkmcnt(8)" ::: "memory");                        \
    __builtin_amdgcn_sched_barrier(0);                                        \
    __builtin_amdgcn_s_setprio(1);                                            \
    MFMA4x2(0, 2, a0, BHI);                                                   \
    __builtin_amdgcn_s_setprio(0);                                            \
    /* ---- P2 ---- */                                                        \
    asm volatile("s_waitcnt lgkmcnt(0)" ::: "memory");                        \
    __builtin_amdgcn_sched_barrier(0);                                        \
    __builtin_amdgcn_s_setprio(1);                                            \
    MFMA4x2(4, 2, a1, BHI);                                                   \
    __builtin_amdgcn_s_setprio(0);                                            \
    /* ---- P3 ---- */                                                        \
    STG((J) + 2, 0, 0);                                                       \
    if ((J) < NK - 2) asm volatile("s_waitcnt vmcnt(2)" ::: "memory");        \
    else              asm volatile("s_waitcnt vmcnt(0)" ::: "memory");        \
    BARRIER();                                                                \
    if ((J) + 1 < NK) {                                                       \
      a0[0][0] = *(const short8*)&sn[aK0];                                    \
      a0[0][1] = *(const short8*)&sn[aK1];                                    \
      a0[1][0] = *(const short8*)&sn[aK0 + 1024];                             \
      a0[1][1] = *(const short8*)&sn[aK1 + 1024];                             \
      a0[2][0] = *(const short8*)&sn[aK0 + 2048];                             \
      a0[2][1] = *(const short8*)&sn[aK1 + 2048];                             \
      a0[3][0] = *(const short8*)&sn[aK0 + 3072];                             \
      a0[3][1] = *(const short8*)&sn[aK1 + 3072];                             \
      BHI[0][0] = *(const short8*)&sn[bK0];                                   \
      BHI[0][1] = *(const short8*)&sn[bK1];                                   \
      BHI[1][0] = *(const short8*)&sn[bK0 + 1024];                            \
      BHI[1][1] = *(const short8*)&sn[bK1 + 1024];                            \
    }                                                                         \
    __builtin_amdgcn_sched_barrier(0);                                        \
    __builtin_amdgcn_s_setprio(1);                                            \
    MFMA4x2(4, 0, a1, BLO);                                                   \
    __builtin_amdgcn_s_setprio(0);                                            \
  }

  // prologue: tile0 complete + A0(1); vmcnt(2) leaves A0(1) in flight
  STG(0, 0, 0); STG(0, 0, 1); STG(0, 1, 0); STG(0, 1, 1); STG(1, 0, 0);
  asm volatile("s_waitcnt vmcnt(2)" ::: "memory");
  BARRIER();

  // pre-read a-lo(0), b-lo(0); drained by first P0's lgkm(4)
  a0[0][0] = *(const short8*)&smem[aK0];
  a0[0][1] = *(const short8*)&smem[aK1];
  a0[1][0] = *(const short8*)&smem[aK0 + 1024];
  a0[1][1] = *(const short8*)&smem[aK1 + 1024];
  a0[2][0] = *(const short8*)&smem[aK0 + 2048];
  a0[2][1] = *(const short8*)&smem[aK1 + 2048];
  a0[3][0] = *(const short8*)&smem[aK0 + 3072];
  a0[3][1] = *(const short8*)&smem[aK1 + 3072];
  bA[0][0] = *(const short8*)&smem[bK0];
  bA[0][1] = *(const short8*)&smem[bK1];
  bA[1][0] = *(const short8*)&smem[bK0 + 1024];
  bA[1][1] = *(const short8*)&smem[bK1 + 1024];

  for (int j = 0; j < NK; j += 2) {
    TILE(j,     bA, bB);
    TILE(j + 1, bB, bA);
  }

  // epilogue: C/D layout col=lane&15, row=(lane>>4)*4+j
  const int erow = hi * 4;
#pragma unroll
  for (int fm = 0; fm < 8; ++fm) {
#pragma unroll
    for (int fn = 0; fn < 4; ++fn) {
      const int cg = n0 + wn * 64 + fn * 16 + lr;
      const float bb = bias[cg];
      const int rbase = m0 + wm * 128 + fm * 16 + erow;
#pragma unroll
      for (int jr = 0; jr < 4; ++jr) {
        const float val = acc[fm][fn][jr] + bb;
        if (OUT_BF16)
          ((u16*)Cout)[(size_t)(rbase + jr) * N + cg] = f2bf(val);
        else
          ((float*)Cout)[(size_t)(rbase + jr) * N + cg] = val;
      }
    }
  }
#undef TILE
#undef MFMA4x2
}

// ---------------- token-0 attention, per (b,h), in-place on V ----------------
__global__ __launch_bounds__(64) void attn0_kernel(u16* __restrict__ V) {
  const int b = blockIdx.x, h = blockIdx.y;
  __shared__ __align__(16) u16 vt[NTOK * 64];
  __shared__ float pb[64];
  const int t = threadIdx.x;
  u16* base = V + (size_t)b * NTOK * CDIM + h * 64;
  for (int idx = t; idx < NTOK * 8; idx += 64) {
    const int m = idx >> 3, g = (idx & 7) * 8;
    *reinterpret_cast<uint4*>(&vt[m * 64 + g]) =
        *reinterpret_cast<const uint4*>(base + (size_t)m * CDIM + g);
  }
  __syncthreads();
  const float qd = bf2f(vt[t]);
  float s_own = -1e30f;
  for (int m = 0; m < NTOK; m++) {
    float p = qd * bf2f(vt[m * 64 + t]);
#pragma unroll
    for (int off = 32; off; off >>= 1) p += __shfl_xor(p, off);
    if (t == m) s_own = p * 0.125f;
  }
  float mx = s_own;
#pragma unroll
  for (int off = 32; off; off >>= 1) mx = fmaxf(mx, __shfl_xor(mx, off));
  const float e = (t < NTOK) ? __expf(s_own - mx) : 0.f;
  float Z = e;
#pragma unroll
  for (int off = 32; off; off >>= 1) Z += __shfl_xor(Z, off);
  pb[t] = e / Z;
  __syncthreads();
  float acc = 0.f;
  for (int m = 0; m < NTOK; m++) acc += pb[m] * bf2f(vt[m * 64 + t]);
  base[t] = f2bf(acc);
}

// ---------------- launch ----------------
extern "C" void kernel_launch(void* const* d_in, const int* in_sizes, int n_in,
                              void* d_out, int out_size, void* d_ws, size_t ws_size,
                              hipStream_t stream) {
  const float* x   = (const float*)d_in[0];
  const float* pos = (const float*)d_in[1];
  const float* Wv  = (const float*)d_in[2];
  const float* bv  = (const float*)d_in[3];
  const float* Wc  = (const float*)d_in[4];
  const float* bc  = (const float*)d_in[5];
  float* out = (float*)d_out;

  u16* T   = (u16*)d_ws;                        // [12800][2048] bf16
  u16* V   = T   + (size_t)MROWS * CDIM;        // [12800][2048] bf16
  u16* WvB = V   + (size_t)MROWS * CDIM;        // [2048][2048]  bf16
  u16* WcB = WvB + (size_t)CDIM * CDIM;         // [1024][2048]  bf16

  {
    int n4a = CDIM * CDIM / 4;
    int n4b = ODIM * CDIM / 4;
    cvt2_kernel<<<(n4a + n4b + 255) / 256, 256, 0, stream>>>(Wv, WvB, n4a, Wc, WcB, n4b);
  }
  prep_kernel<<<BATCH * 32, 256, 0, stream>>>(x, pos, T);

  // GEMM1: [12800,2048]x[2048,2048]^T -> V ; grid 400 (%8==0)
  gemm256<1><<<(MROWS / 256) * (CDIM / 256), 512, 0, stream>>>(
      T, WvB, bv, V, MROWS, CDIM, CDIM, CDIM / 256);

  attn0_kernel<<<dim3(BATCH, NHEADS), 64, 0, stream>>>(V);

  // GEMM2: [12800,2048]x[1024,2048]^T -> out ; grid 200 (%8==0)
  gemm256<0><<<(MROWS / 256) * (ODIM / 256), 512, 0, stream>>>(
      V, WcB, bc, out, MROWS, ODIM, CDIM, ODIM / 256);
}

// Round 8
// 292.133 us; speedup vs baseline: 1.5225x; 1.5225x over previous
//
#include <hip/hip_runtime.h>
#include <stdint.h>

#define BATCH  256
#define CDIM   2048
#define HW     49
#define NTOK   50
#define MROWS  (BATCH * NTOK)   // 12800
#define ODIM   1024
#define NHEADS 32

typedef __attribute__((ext_vector_type(8)))  short short8;
typedef __attribute__((ext_vector_type(4)))  float f32x4;
typedef __attribute__((ext_vector_type(16))) float f32x16;
typedef unsigned short u16;
typedef unsigned int   u32;

__device__ __forceinline__ float bf2f(u16 u) {
  union { u32 i; float f; } v; v.i = ((u32)u) << 16; return v.f;
}
__device__ __forceinline__ u16 f2bf(float f) {
  union { float f; u32 i; } v; v.f = f;
  u32 r = v.i + 0x7fffu + ((v.i >> 16) & 1u);   // round-to-nearest-even
  return (u16)(r >> 16);
}

// async global->LDS, 16 bytes per lane (wave-uniform base + lane*16 dest)
__device__ __forceinline__ void async16(const void* g, void* l) {
  __builtin_amdgcn_global_load_lds(
      (const __attribute__((address_space(1))) u32*)g,
      (__attribute__((address_space(3))) u32*)l, 16, 0, 0);
}

// ---------------- fused fp32->bf16 weight convert + token prep ----------------
// blocks [0, nCvt): convert Wv then Wc (flat float4 indexing)
// blocks [nCvt, nCvt+8192): prep x[B,C,49] -> T[B*50, C] bf16
__global__ __launch_bounds__(256) void cvt_prep_kernel(
    const float* __restrict__ Wv, u16* __restrict__ WvB, int n4a,
    const float* __restrict__ Wc, u16* __restrict__ WcB, int n4b,
    const float* __restrict__ x, const float* __restrict__ pos,
    u16* __restrict__ T, int nCvt) {
  if (blockIdx.x < (unsigned)nCvt) {
    int i = blockIdx.x * 256 + threadIdx.x;
    const float* src; u16* dst; int idx;
    if (i < n4a) { src = Wv; dst = WvB; idx = i; }
    else {
      idx = i - n4a;
      if (idx >= n4b) return;
      src = Wc; dst = WcB;
    }
    float4 v = reinterpret_cast<const float4*>(src)[idx];
    ushort4 o;
    o.x = f2bf(v.x); o.y = f2bf(v.y); o.z = f2bf(v.z); o.w = f2bf(v.w);
    reinterpret_cast<ushort4*>(dst)[idx] = o;
    return;
  }
  const int blk = blockIdx.x - nCvt;
  const int b  = blk >> 5;             // 32 chunks of 64 channels
  const int c0 = (blk & 31) * 64;
  __shared__ float xs[64 * HW];
  __shared__ float mean[64];
  const float* src = x + ((size_t)b * CDIM + c0) * HW;  // 3136 floats
  for (int i = threadIdx.x; i < 64 * HW / 4; i += 256)
    reinterpret_cast<float4*>(xs)[i] = reinterpret_cast<const float4*>(src)[i];
  __syncthreads();
  if (threadIdx.x < 64) {
    float s = 0.f;
#pragma unroll
    for (int j = 0; j < HW; j++) s += xs[threadIdx.x * HW + j];
    mean[threadIdx.x] = s * (1.0f / 49.0f);
  }
  __syncthreads();
  for (int wi = threadIdx.x; wi < NTOK * 8; wi += 256) {
    const int n = wi >> 3;
    const int g = (wi & 7) * 8;
    alignas(16) u16 ov[8];
#pragma unroll
    for (int u = 0; u < 8; u++) {
      const int c = g + u;
      float val = (n == 0) ? mean[c] : xs[c * HW + (n - 1)];
      val += pos[n * CDIM + c0 + c];
      ov[u] = f2bf(val);
    }
    *reinterpret_cast<uint4*>(&T[((size_t)b * NTOK + n) * CDIM + c0 + g]) =
        *reinterpret_cast<const uint4*>(ov);
  }
}

// ---------------- 256x256 GEMM (B^T), R2-proven lockstep schedule, ----------
// ---------------- now on v_mfma_f32_32x32x16_bf16 ---------------------------
// Per wave: 128x64 output = 4 mtiles(32) x 2 ntiles(32); acc[4][2] f32x16
// (128 AGPR, same as before). A/B lane mapping: row = lane&31,
// k = (lane>>5)*8 + j. C/D: col=lane&31, row=(reg&3)+8*(reg>>2)+4*(lane>>5)
// [m74/m101]. Quadrant phases P0..P3 identical to R2 (passed twice):
//   P0: read a-lo(8) + b-lo(4); STG A1(j+1); BAR; lgkm0; Q(mt01,nt0); BAR
//   P1: read b-hi(4);           STG B0(j+1); BAR; lgkm0; Q(mt01,nt1); BAR
//   P2: read a-hi(8);           STG B1(j+1); BAR; lgkm0; Q(mt23,nt1); BAR
//   P3: read b-lo(4);           STG A0(j+2); BAR; lgkm0; Q(mt23,nt0);
//       vmcnt(2|0); BAR
// vmcnt(2)@P3: queue=[A0(j+1),A1,B0,B1(j+1),A0(j+2)] -> drains all but
// A0(j+2) => tile j+1 landed. A0(j+2) targets the buffer tile j used;
// tile j+1 reads the other buffer; j+2's reads gated by j+1's vmcnt+BAR.
template<int OUT_BF16>
__global__ __launch_bounds__(512, 2)
void gemm256(const u16* __restrict__ A, const u16* __restrict__ Bm,
             const float* __restrict__ bias, void* __restrict__ Cout,
             int M, int N, int K, int nbx) {
  __shared__ __align__(16) u16 smem[65536];   // 128 KiB

  const int NK = K >> 6;
  const int t = threadIdx.x;
  const int lane = t & 63;
  const int wid = t >> 6;
  const int wm = wid >> 2;          // 0..1
  const int wn = wid & 3;           // 0..3

  // bijective XCD swizzle (gridDim.x % 8 == 0)
  const int nwg = gridDim.x;
  const int cpx = nwg >> 3;
  const int orig = blockIdx.x;
  const int swz = (orig & 7) * cpx + (orig >> 3);
  const int bx = swz % nbx;
  const int by = swz / nbx;
  const int m0 = by * 256, n0 = bx * 256;

  // staging source (pre-swizzled octet so linear LDS dest = swizzled layout)
  const int tr  = t >> 3;
  const int to8 = ((t & 7) ^ (tr & 7)) << 3;
  const int t8  = t << 3;
  const u16* pA0 = A  + (size_t)(m0 + tr) * K + to8;
  const u16* pB0 = Bm + (size_t)(n0 + tr) * K + to8;

  // ds_read offsets: row = {wm*128|16384+wn*64} + mt/nt*32 + (lane&31);
  // k granule g = kq*2 + (lane>>5), swizzled g^=row&7 (= lane&7)
  const int l31 = lane & 31, hi5 = lane >> 5;
  const int sx = l31 & 7;
  int aG[4];
#pragma unroll
  for (int kq = 0; kq < 4; ++kq) aG[kq] = (((kq * 2 + hi5) ^ sx) << 3);
  const int aBase = ((wm * 128 + l31) << 6);
  const int bBase = 16384 + ((wn * 64 + l31) << 6);

  f32x16 acc[4][2] = {};
  short8 a[2][4], a2[2][4], b[4];

  auto STG = [&](int kti, int isB, int h) {
    if (kti < NK) {
      const u16* g = (isB ? pB0 : pA0) + (size_t)(h * 128) * K + kti * 64;
      u16* l = &smem[((kti & 1) << 15) + (isB << 14) + (h << 13) + t8];
      async16(g, l);
      async16(g + (size_t)64 * K, l + 4096);
    }
  };

#define MFMAQ(MT0, NT, AARR)                                                  \
  _Pragma("unroll")                                                           \
  for (int kq = 0; kq < 4; ++kq) {                                            \
    acc[(MT0)][(NT)] = __builtin_amdgcn_mfma_f32_32x32x16_bf16(               \
        AARR[0][kq], b[kq], acc[(MT0)][(NT)], 0, 0, 0);                       \
    acc[(MT0) + 1][(NT)] = __builtin_amdgcn_mfma_f32_32x32x16_bf16(           \
        AARR[1][kq], b[kq], acc[(MT0) + 1][(NT)], 0, 0, 0);                   \
  }

  // prologue: tile0 complete + A0(1); vmcnt(2) leaves A0(1) in flight
  STG(0, 0, 0); STG(0, 0, 1); STG(0, 1, 0); STG(0, 1, 1); STG(1, 0, 0);
  asm volatile("s_waitcnt vmcnt(2)" ::: "memory");
  __builtin_amdgcn_s_barrier();

  for (int j = 0; j < NK; ++j) {
    const u16* sa = &smem[(j & 1) << 15];

    // ---- P0: a-lo + b-lo -> Q(mt0/1, nt0) ----
#pragma unroll
    for (int mt = 0; mt < 2; ++mt)
#pragma unroll
      for (int kq = 0; kq < 4; ++kq)
        a[mt][kq] = *(const short8*)&sa[aBase + mt * 2048 + aG[kq]];
#pragma unroll
    for (int kq = 0; kq < 4; ++kq)
      b[kq] = *(const short8*)&sa[bBase + aG[kq]];
    STG(j + 1, 0, 1);
    __builtin_amdgcn_s_barrier();
    asm volatile("s_waitcnt lgkmcnt(0)" ::: "memory");
    __builtin_amdgcn_sched_barrier(0);
    __builtin_amdgcn_s_setprio(1);
    MFMAQ(0, 0, a);
    __builtin_amdgcn_s_setprio(0);
    __builtin_amdgcn_s_barrier();

    // ---- P1: b-hi -> Q(mt0/1, nt1) ----
#pragma unroll
    for (int kq = 0; kq < 4; ++kq)
      b[kq] = *(const short8*)&sa[bBase + 2048 + aG[kq]];
    STG(j + 1, 1, 0);
    __builtin_amdgcn_s_barrier();
    asm volatile("s_waitcnt lgkmcnt(0)" ::: "memory");
    __builtin_amdgcn_sched_barrier(0);
    __builtin_amdgcn_s_setprio(1);
    MFMAQ(0, 1, a);
    __builtin_amdgcn_s_setprio(0);
    __builtin_amdgcn_s_barrier();

    // ---- P2: a-hi -> Q(mt2/3, nt1) ----
#pragma unroll
    for (int mt = 0; mt < 2; ++mt)
#pragma unroll
      for (int kq = 0; kq < 4; ++kq)
        a2[mt][kq] = *(const short8*)&sa[aBase + (2 + mt) * 2048 + aG[kq]];
    STG(j + 1, 1, 1);
    __builtin_amdgcn_s_barrier();
    asm volatile("s_waitcnt lgkmcnt(0)" ::: "memory");
    __builtin_amdgcn_sched_barrier(0);
    __builtin_amdgcn_s_setprio(1);
    MFMAQ(2, 1, a2);
    __builtin_amdgcn_s_setprio(0);
    __builtin_amdgcn_s_barrier();

    // ---- P3: b-lo (reload) -> Q(mt2/3, nt0) ----
#pragma unroll
    for (int kq = 0; kq < 4; ++kq)
      b[kq] = *(const short8*)&sa[bBase + aG[kq]];
    STG(j + 2, 0, 0);
    __builtin_amdgcn_s_barrier();
    asm volatile("s_waitcnt lgkmcnt(0)" ::: "memory");
    __builtin_amdgcn_sched_barrier(0);
    __builtin_amdgcn_s_setprio(1);
    MFMAQ(2, 0, a2);
    __builtin_amdgcn_s_setprio(0);
    if (j < NK - 2) asm volatile("s_waitcnt vmcnt(2)" ::: "memory");
    else            asm volatile("s_waitcnt vmcnt(0)" ::: "memory");
    __builtin_amdgcn_s_barrier();
  }

  // epilogue: 32x32 C/D layout col=lane&31, row=(r&3)+8*(r>>2)+4*hi5
#pragma unroll
  for (int mt = 0; mt < 4; ++mt) {
#pragma unroll
    for (int nt = 0; nt < 2; ++nt) {
      const int cg = n0 + wn * 64 + nt * 32 + l31;
      const float bb = bias[cg];
      const int rb = m0 + wm * 128 + mt * 32 + 4 * hi5;
#pragma unroll
      for (int r = 0; r < 16; ++r) {
        const int rg = rb + (r & 3) + 8 * (r >> 2);
        const float val = acc[mt][nt][r] + bb;
        if (OUT_BF16)
          ((u16*)Cout)[(size_t)rg * N + cg] = f2bf(val);
        else
          ((float*)Cout)[(size_t)rg * N + cg] = val;
      }
    }
  }
#undef MFMAQ
}

// ---------------- token-0 attention, per (b,h), in-place on V ----------------
__global__ __launch_bounds__(64) void attn0_kernel(u16* __restrict__ V) {
  const int b = blockIdx.x, h = blockIdx.y;
  __shared__ __align__(16) u16 vt[NTOK * 64];
  __shared__ float pb[64];
  const int t = threadIdx.x;
  u16* base = V + (size_t)b * NTOK * CDIM + h * 64;
  for (int idx = t; idx < NTOK * 8; idx += 64) {
    const int m = idx >> 3, g = (idx & 7) * 8;
    *reinterpret_cast<uint4*>(&vt[m * 64 + g]) =
        *reinterpret_cast<const uint4*>(base + (size_t)m * CDIM + g);
  }
  __syncthreads();
  const float qd = bf2f(vt[t]);
  float s_own = -1e30f;
  for (int m = 0; m < NTOK; m++) {
    float p = qd * bf2f(vt[m * 64 + t]);
#pragma unroll
    for (int off = 32; off; off >>= 1) p += __shfl_xor(p, off);
    if (t == m) s_own = p * 0.125f;
  }
  float mx = s_own;
#pragma unroll
  for (int off = 32; off; off >>= 1) mx = fmaxf(mx, __shfl_xor(mx, off));
  const float e = (t < NTOK) ? __expf(s_own - mx) : 0.f;
  float Z = e;
#pragma unroll
  for (int off = 32; off; off >>= 1) Z += __shfl_xor(Z, off);
  pb[t] = e / Z;
  __syncthreads();
  float acc = 0.f;
  for (int m = 0; m < NTOK; m++) acc += pb[m] * bf2f(vt[m * 64 + t]);
  base[t] = f2bf(acc);
}

// ---------------- launch ----------------
extern "C" void kernel_launch(void* const* d_in, const int* in_sizes, int n_in,
                              void* d_out, int out_size, void* d_ws, size_t ws_size,
                              hipStream_t stream) {
  const float* x   = (const float*)d_in[0];
  const float* pos = (const float*)d_in[1];
  const float* Wv  = (const float*)d_in[2];
  const float* bv  = (const float*)d_in[3];
  const float* Wc  = (const float*)d_in[4];
  const float* bc  = (const float*)d_in[5];
  float* out = (float*)d_out;

  u16* T   = (u16*)d_ws;                        // [12800][2048] bf16
  u16* V   = T   + (size_t)MROWS * CDIM;        // [12800][2048] bf16
  u16* WvB = V   + (size_t)MROWS * CDIM;        // [2048][2048]  bf16
  u16* WcB = WvB + (size_t)CDIM * CDIM;         // [1024][2048]  bf16

  {
    int n4a = CDIM * CDIM / 4;                  // 1048576
    int n4b = ODIM * CDIM / 4;                  // 524288
    int nCvt = (n4a + n4b + 255) / 256;         // 6144
    cvt_prep_kernel<<<nCvt + BATCH * 32, 256, 0, stream>>>(
        Wv, WvB, n4a, Wc, WcB, n4b, x, pos, T, nCvt);
  }

  // GEMM1: [12800,2048]x[2048,2048]^T -> V ; grid 400 (%8==0)
  gemm256<1><<<(MROWS / 256) * (CDIM / 256), 512, 0, stream>>>(
      T, WvB, bv, V, MROWS, CDIM, CDIM, CDIM / 256);

  attn0_kernel<<<dim3(BATCH, NHEADS), 64, 0, stream>>>(V);

  // GEMM2: [12800,2048]x[1024,2048]^T -> out ; grid 200 (%8==0)
  gemm256<0><<<(MROWS / 256) * (ODIM / 256), 512, 0, stream>>>(
      V, WcB, bc, out, MROWS, ODIM, CDIM, ODIM / 256);
}

// Round 9
// 290.376 us; speedup vs baseline: 1.5317x; 1.0061x over previous
//
#include <hip/hip_runtime.h>
#include <stdint.h>

#define BATCH  256
#define CDIM   2048
#define HW     49
#define NTOK   50
#define MROWS  (BATCH * NTOK)   // 12800
#define ODIM   1024
#define NHEADS 32

typedef __attribute__((ext_vector_type(8))) short short8;
typedef __attribute__((ext_vector_type(4))) float f32x4;
typedef unsigned short u16;
typedef unsigned int   u32;

__device__ __forceinline__ float bf2f(u16 u) {
  union { u32 i; float f; } v; v.i = ((u32)u) << 16; return v.f;
}
__device__ __forceinline__ u16 f2bf(float f) {
  union { float f; u32 i; } v; v.f = f;
  u32 r = v.i + 0x7fffu + ((v.i >> 16) & 1u);   // round-to-nearest-even
  return (u16)(r >> 16);
}

// async global->LDS, 16 bytes per lane (wave-uniform base + lane*16 dest)
__device__ __forceinline__ void async16(const void* g, void* l) {
  __builtin_amdgcn_global_load_lds(
      (const __attribute__((address_space(1))) u32*)g,
      (__attribute__((address_space(3))) u32*)l, 16, 0, 0);
}

// barrier that is ALSO a compiler memory fence (R5 lesson)
#define BARRIER() asm volatile("s_barrier" ::: "memory")

// ---------------- fused fp32->bf16 weight convert + token prep ----------------
__global__ __launch_bounds__(256) void cvt_prep_kernel(
    const float* __restrict__ Wv, u16* __restrict__ WvB, int n4a,
    const float* __restrict__ Wc, u16* __restrict__ WcB, int n4b,
    const float* __restrict__ x, const float* __restrict__ pos,
    u16* __restrict__ T, int nCvt) {
  if (blockIdx.x < (unsigned)nCvt) {
    int i = blockIdx.x * 256 + threadIdx.x;
    const float* src; u16* dst; int idx;
    if (i < n4a) { src = Wv; dst = WvB; idx = i; }
    else {
      idx = i - n4a;
      if (idx >= n4b) return;
      src = Wc; dst = WcB;
    }
    float4 v = reinterpret_cast<const float4*>(src)[idx];
    ushort4 o;
    o.x = f2bf(v.x); o.y = f2bf(v.y); o.z = f2bf(v.z); o.w = f2bf(v.w);
    reinterpret_cast<ushort4*>(dst)[idx] = o;
    return;
  }
  const int blk = blockIdx.x - nCvt;
  const int b  = blk >> 5;             // 32 chunks of 64 channels
  const int c0 = (blk & 31) * 64;
  __shared__ float xs[64 * HW];
  __shared__ float mean[64];
  const float* src = x + ((size_t)b * CDIM + c0) * HW;  // 3136 floats
  for (int i = threadIdx.x; i < 64 * HW / 4; i += 256)
    reinterpret_cast<float4*>(xs)[i] = reinterpret_cast<const float4*>(src)[i];
  __syncthreads();
  if (threadIdx.x < 64) {
    float s = 0.f;
#pragma unroll
    for (int j = 0; j < HW; j++) s += xs[threadIdx.x * HW + j];
    mean[threadIdx.x] = s * (1.0f / 49.0f);
  }
  __syncthreads();
  for (int wi = threadIdx.x; wi < NTOK * 8; wi += 256) {
    const int n = wi >> 3;
    const int g = (wi & 7) * 8;
    alignas(16) u16 ov[8];
#pragma unroll
    for (int u = 0; u < 8; u++) {
      const int c = g + u;
      float val = (n == 0) ? mean[c] : xs[c * HW + (n - 1)];
      val += pos[n * CDIM + c0 + c];
      ov[u] = f2bf(val);
    }
    *reinterpret_cast<uint4*>(&T[((size_t)b * NTOK + n) * CDIM + c0 + g]) =
        *reinterpret_cast<const uint4*>(ov);
  }
}

// ---------------- 256x256 lockstep GEMM (B^T): C = A*Bm^T + bias ------------
// R2 skeleton (2 asm-fenced barriers/phase, 16x16 MFMA, 0-conflict swizzled
// reads) with: all 8 staging loads front-loaded at P0 (3-phase vmcnt lead),
// both B halves held live (P3 read-free, 24 reads/tile = floor).
//   P0: read a-lo(8)+b-lo(4); STG all of tile j+1 (8 ld); BAR; lgkm0;
//       Q(lo,lo); BAR
//   P1: read b-hi(4); BAR; lgkm0; Q(lo,hi); BAR
//   P2: read a-hi(8) [overwrites a]; BAR; lgkm0; Q(hi,hi); BAR
//   P3: Q(hi,lo) [regs only]; vmcnt(0) [tile j+1 landed, 3-phase lead]; BAR
// WAR: STG@P0(j) writes buf (j+1)&1, last read by tile j-1 (drained at its
// P2 lgkm0, ordered by the tile-end barrier). All barriers asm memory-fenced
// so no LDS/DMA op crosses at compile time. vmcnt(0)@P3 + fence orders all
// staging before the next tile's reads.
template<int OUT_BF16>
__global__ __launch_bounds__(512, 2)
void gemm256(const u16* __restrict__ A, const u16* __restrict__ Bm,
             const float* __restrict__ bias, void* __restrict__ Cout,
             int M, int N, int K, int nbx) {
  __shared__ __align__(16) u16 smem[65536];   // 128 KiB

  const int NK = K >> 6;
  const int t = threadIdx.x;
  const int lane = t & 63;
  const int wid = t >> 6;
  const int wm = wid >> 2;          // 0..1
  const int wn = wid & 3;           // 0..3

  // bijective XCD swizzle (gridDim.x % 8 == 0)
  const int nwg = gridDim.x;
  const int cpx = nwg >> 3;
  const int orig = blockIdx.x;
  const int swz = (orig & 7) * cpx + (orig >> 3);
  const int bx = swz % nbx;
  const int by = swz / nbx;
  const int m0 = by * 256, n0 = bx * 256;

  // staging source (pre-swizzled octet so linear LDS dest = swizzled layout)
  const int tr  = t >> 3;
  const int to8 = ((t & 7) ^ (tr & 7)) << 3;
  const int t8  = t << 3;
  const u16* pA0 = A  + (size_t)(m0 + tr) * K + to8;
  const u16* pB0 = Bm + (size_t)(n0 + tr) * K + to8;

  // ds_read offsets (elements), granule g=kk*4+hi XORed with row&7 (R2 exact)
  const int lr = lane & 15, hi = lane >> 4;
  const int sx = lr & 7;
  const int aK0 = ((wm * 128 + lr) << 6) + (((0 + hi) ^ sx) << 3);
  const int aK1 = ((wm * 128 + lr) << 6) + (((4 + hi) ^ sx) << 3);
  const int bK0 = 16384 + ((wn * 64 + lr) << 6) + (((0 + hi) ^ sx) << 3);
  const int bK1 = 16384 + ((wn * 64 + lr) << 6) + (((4 + hi) ^ sx) << 3);

  f32x4 acc[8][4] = {};
  short8 a[4][2], b[4][2];   // a: lo then hi (reused); b: lo AND hi live

  auto STG = [&](int kti, int isB, int h) {
    if (kti < NK) {
      const u16* g = (isB ? pB0 : pA0) + (size_t)(h * 128) * K + kti * 64;
      u16* l = &smem[((kti & 1) << 15) + (isB << 14) + (h << 13) + t8];
      async16(g, l);
      async16(g + (size_t)64 * K, l + 4096);
    }
  };

#define MFMA4x2(AM, BN0, ACCM, ACCN)                                          \
  _Pragma("unroll")                                                           \
  for (int fm = 0; fm < 4; ++fm) {                                            \
    _Pragma("unroll")                                                         \
    for (int fn = 0; fn < 2; ++fn) {                                          \
      acc[(ACCM) + fm][(ACCN) + fn] = __builtin_amdgcn_mfma_f32_16x16x32_bf16(\
          a[fm][0], b[(BN0) + fn][0], acc[(ACCM) + fm][(ACCN) + fn], 0, 0, 0);\
      acc[(ACCM) + fm][(ACCN) + fn] = __builtin_amdgcn_mfma_f32_16x16x32_bf16(\
          a[fm][1], b[(BN0) + fn][1], acc[(ACCM) + fm][(ACCN) + fn], 0, 0, 0);\
    }                                                                         \
  }

  // prologue: stage all of tile 0
  STG(0, 0, 0); STG(0, 0, 1); STG(0, 1, 0); STG(0, 1, 1);
  asm volatile("s_waitcnt vmcnt(0)" ::: "memory");
  BARRIER();

  for (int j = 0; j < NK; ++j) {
    const u16* sa = &smem[(j & 1) << 15];

    // ---- P0: a-lo + b-lo; stage ALL of tile j+1 ----
#pragma unroll
    for (int f = 0; f < 4; ++f) {
      a[f][0] = *(const short8*)&sa[aK0 + f * 1024];
      a[f][1] = *(const short8*)&sa[aK1 + f * 1024];
    }
#pragma unroll
    for (int f = 0; f < 2; ++f) {
      b[f][0] = *(const short8*)&sa[bK0 + f * 1024];
      b[f][1] = *(const short8*)&sa[bK1 + f * 1024];
    }
    STG(j + 1, 0, 0); STG(j + 1, 0, 1); STG(j + 1, 1, 0); STG(j + 1, 1, 1);
    BARRIER();
    asm volatile("s_waitcnt lgkmcnt(0)" ::: "memory");
    __builtin_amdgcn_sched_barrier(0);
    __builtin_amdgcn_s_setprio(1);
    MFMA4x2(lo, 0, 0, 0);
    __builtin_amdgcn_s_setprio(0);
    BARRIER();

    // ---- P1: b-hi ----
#pragma unroll
    for (int f = 2; f < 4; ++f) {
      b[f][0] = *(const short8*)&sa[bK0 + f * 1024];
      b[f][1] = *(const short8*)&sa[bK1 + f * 1024];
    }
    BARRIER();
    asm volatile("s_waitcnt lgkmcnt(0)" ::: "memory");
    __builtin_amdgcn_sched_barrier(0);
    __builtin_amdgcn_s_setprio(1);
    MFMA4x2(lo, 2, 0, 2);
    __builtin_amdgcn_s_setprio(0);
    BARRIER();

    // ---- P2: a-hi (overwrites a) ----
#pragma unroll
    for (int f = 0; f < 4; ++f) {
      a[f][0] = *(const short8*)&sa[aK0 + (4 + f) * 1024];
      a[f][1] = *(const short8*)&sa[aK1 + (4 + f) * 1024];
    }
    BARRIER();
    asm volatile("s_waitcnt lgkmcnt(0)" ::: "memory");
    __builtin_amdgcn_sched_barrier(0);
    __builtin_amdgcn_s_setprio(1);
    MFMA4x2(hi, 2, 4, 2);
    __builtin_amdgcn_s_setprio(0);
    BARRIER();

    // ---- P3: register-only quadrant; drain tile j+1; tile-end barrier ----
    __builtin_amdgcn_s_setprio(1);
    MFMA4x2(hi, 0, 4, 0);
    __builtin_amdgcn_s_setprio(0);
    asm volatile("s_waitcnt vmcnt(0)" ::: "memory");
    BARRIER();
  }

  // epilogue: C/D layout col=lane&15, row=(lane>>4)*4+j  [m89/m91]
  const int erow = hi * 4;
#pragma unroll
  for (int fm = 0; fm < 8; ++fm) {
#pragma unroll
    for (int fn = 0; fn < 4; ++fn) {
      const int cg = n0 + wn * 64 + fn * 16 + lr;
      const float bb = bias[cg];
      const int rbase = m0 + wm * 128 + fm * 16 + erow;
#pragma unroll
      for (int jr = 0; jr < 4; ++jr) {
        const float val = acc[fm][fn][jr] + bb;
        if (OUT_BF16)
          ((u16*)Cout)[(size_t)(rbase + jr) * N + cg] = f2bf(val);
        else
          ((float*)Cout)[(size_t)(rbase + jr) * N + cg] = val;
      }
    }
  }
#undef MFMA4x2
}

// ---------------- token-0 attention, per (b,h), in-place on V ----------------
__global__ __launch_bounds__(64) void attn0_kernel(u16* __restrict__ V) {
  const int b = blockIdx.x, h = blockIdx.y;
  __shared__ __align__(16) u16 vt[NTOK * 64];
  __shared__ float pb[64];
  const int t = threadIdx.x;
  u16* base = V + (size_t)b * NTOK * CDIM + h * 64;
  for (int idx = t; idx < NTOK * 8; idx += 64) {
    const int m = idx >> 3, g = (idx & 7) * 8;
    *reinterpret_cast<uint4*>(&vt[m * 64 + g]) =
        *reinterpret_cast<const uint4*>(base + (size_t)m * CDIM + g);
  }
  __syncthreads();
  const float qd = bf2f(vt[t]);
  float s_own = -1e30f;
  for (int m = 0; m < NTOK; m++) {
    float p = qd * bf2f(vt[m * 64 + t]);
#pragma unroll
    for (int off = 32; off; off >>= 1) p += __shfl_xor(p, off);
    if (t == m) s_own = p * 0.125f;
  }
  float mx = s_own;
#pragma unroll
  for (int off = 32; off; off >>= 1) mx = fmaxf(mx, __shfl_xor(mx, off));
  const float e = (t < NTOK) ? __expf(s_own - mx) : 0.f;
  float Z = e;
#pragma unroll
  for (int off = 32; off; off >>= 1) Z += __shfl_xor(Z, off);
  pb[t] = e / Z;
  __syncthreads();
  float acc = 0.f;
  for (int m = 0; m < NTOK; m++) acc += pb[m] * bf2f(vt[m * 64 + t]);
  base[t] = f2bf(acc);
}

// ---------------- launch ----------------
extern "C" void kernel_launch(void* const* d_in, const int* in_sizes, int n_in,
                              void* d_out, int out_size, void* d_ws, size_t ws_size,
                              hipStream_t stream) {
  const float* x   = (const float*)d_in[0];
  const float* pos = (const float*)d_in[1];
  const float* Wv  = (const float*)d_in[2];
  const float* bv  = (const float*)d_in[3];
  const float* Wc  = (const float*)d_in[4];
  const float* bc  = (const float*)d_in[5];
  float* out = (float*)d_out;

  u16* T   = (u16*)d_ws;                        // [12800][2048] bf16
  u16* V   = T   + (size_t)MROWS * CDIM;        // [12800][2048] bf16
  u16* WvB = V   + (size_t)MROWS * CDIM;        // [2048][2048]  bf16
  u16* WcB = WvB + (size_t)CDIM * CDIM;         // [1024][2048]  bf16

  {
    int n4a = CDIM * CDIM / 4;                  // 1048576
    int n4b = ODIM * CDIM / 4;                  // 524288
    int nCvt = (n4a + n4b + 255) / 256;         // 6144
    cvt_prep_kernel<<<nCvt + BATCH * 32, 256, 0, stream>>>(
        Wv, WvB, n4a, Wc, WcB, n4b, x, pos, T, nCvt);
  }

  // GEMM1: [12800,2048]x[2048,2048]^T -> V ; grid 400 (%8==0)
  gemm256<1><<<(MROWS / 256) * (CDIM / 256), 512, 0, stream>>>(
      T, WvB, bv, V, MROWS, CDIM, CDIM, CDIM / 256);

  attn0_kernel<<<dim3(BATCH, NHEADS), 64, 0, stream>>>(V);

  // GEMM2: [12800,2048]x[1024,2048]^T -> out ; grid 200 (%8==0)
  gemm256<0><<<(MROWS / 256) * (ODIM / 256), 512, 0, stream>>>(
      V, WcB, bc, out, MROWS, ODIM, CDIM, ODIM / 256);
}

// Round 10
// 288.174 us; speedup vs baseline: 1.5434x; 1.0076x over previous
//
#include <hip/hip_runtime.h>
#include <stdint.h>

#define BATCH  256
#define CDIM   2048
#define HW     49
#define NTOK   50
#define MROWS  (BATCH * NTOK)   // 12800
#define ODIM   1024
#define NHEADS 32

typedef __attribute__((ext_vector_type(8))) short short8;
typedef __attribute__((ext_vector_type(4))) float f32x4;
typedef unsigned short u16;
typedef unsigned int   u32;

__device__ __forceinline__ float bf2f(u16 u) {
  union { u32 i; float f; } v; v.i = ((u32)u) << 16; return v.f;
}
__device__ __forceinline__ u16 f2bf(float f) {
  union { float f; u32 i; } v; v.f = f;
  u32 r = v.i + 0x7fffu + ((v.i >> 16) & 1u);   // round-to-nearest-even
  return (u16)(r >> 16);
}

// async global->LDS, 16 bytes per lane (wave-uniform base + lane*16 dest)
__device__ __forceinline__ void async16(const void* g, void* l) {
  __builtin_amdgcn_global_load_lds(
      (const __attribute__((address_space(1))) u32*)g,
      (__attribute__((address_space(3))) u32*)l, 16, 0, 0);
}

// barrier that is ALSO a compiler memory fence (R5 lesson)
#define BARRIER() asm volatile("s_barrier" ::: "memory")

// ---------------- fused fp32->bf16 weight convert + token prep ----------------
__global__ __launch_bounds__(256) void cvt_prep_kernel(
    const float* __restrict__ Wv, u16* __restrict__ WvB, int n4a,
    const float* __restrict__ Wc, u16* __restrict__ WcB, int n4b,
    const float* __restrict__ x, const float* __restrict__ pos,
    u16* __restrict__ T, int nCvt) {
  if (blockIdx.x < (unsigned)nCvt) {
    int i = blockIdx.x * 256 + threadIdx.x;
    const float* src; u16* dst; int idx;
    if (i < n4a) { src = Wv; dst = WvB; idx = i; }
    else {
      idx = i - n4a;
      if (idx >= n4b) return;
      src = Wc; dst = WcB;
    }
    float4 v = reinterpret_cast<const float4*>(src)[idx];
    ushort4 o;
    o.x = f2bf(v.x); o.y = f2bf(v.y); o.z = f2bf(v.z); o.w = f2bf(v.w);
    reinterpret_cast<ushort4*>(dst)[idx] = o;
    return;
  }
  const int blk = blockIdx.x - nCvt;
  const int b  = blk >> 5;             // 32 chunks of 64 channels
  const int c0 = (blk & 31) * 64;
  __shared__ float xs[64 * HW];
  __shared__ float mean[64];
  const float* src = x + ((size_t)b * CDIM + c0) * HW;  // 3136 floats
  for (int i = threadIdx.x; i < 64 * HW / 4; i += 256)
    reinterpret_cast<float4*>(xs)[i] = reinterpret_cast<const float4*>(src)[i];
  __syncthreads();
  if (threadIdx.x < 64) {
    float s = 0.f;
#pragma unroll
    for (int j = 0; j < HW; j++) s += xs[threadIdx.x * HW + j];
    mean[threadIdx.x] = s * (1.0f / 49.0f);
  }
  __syncthreads();
  for (int wi = threadIdx.x; wi < NTOK * 8; wi += 256) {
    const int n = wi >> 3;
    const int g = (wi & 7) * 8;
    alignas(16) u16 ov[8];
#pragma unroll
    for (int u = 0; u < 8; u++) {
      const int c = g + u;
      float val = (n == 0) ? mean[c] : xs[c * HW + (n - 1)];
      val += pos[n * CDIM + c0 + c];
      ov[u] = f2bf(val);
    }
    *reinterpret_cast<uint4*>(&T[((size_t)b * NTOK + n) * CDIM + c0 + g]) =
        *reinterpret_cast<const uint4*>(ov);
  }
}

// ---------------- 256x256 GEMM (B^T): C = A*Bm^T + bias ---------------------
// R9 ledger with TWO phases per K-tile (4 barriers, 2 lgkm joins) instead of
// four (8 barriers, 4 joins) — the controlled variable this round.
//   PhA: read a-lo(8)+b-lo(4)+b-hi(4); STG all of tile j+1 (8 ld); BAR;
//        lgkm0; 32 MFMA (Q(loM,loN)+Q(loM,hiN)); BAR
//   PhB: read a-hi(8) [overwrites a]; BAR; lgkm0;
//        32 MFMA (Q(hiM,hiN)+Q(hiM,loN)); vmcnt(0); BAR
// WAR: STG@PhA(j) writes buf (j+1)&1; its last readers were tile j-1's PhB
// a-hi reads, drained at j-1's lgkm(0) before the fenced tile-end barrier.
// RAW: tile j+1 reads come after vmcnt(0)+BAR at end of tile j; the drained
// loads were issued ~2 phases (~2500 cy) earlier. All barriers asm-fenced.
template<int OUT_BF16>
__global__ __launch_bounds__(512, 2)
void gemm256(const u16* __restrict__ A, const u16* __restrict__ Bm,
             const float* __restrict__ bias, void* __restrict__ Cout,
             int M, int N, int K, int nbx) {
  __shared__ __align__(16) u16 smem[65536];   // 128 KiB

  const int NK = K >> 6;
  const int t = threadIdx.x;
  const int lane = t & 63;
  const int wid = t >> 6;
  const int wm = wid >> 2;          // 0..1
  const int wn = wid & 3;           // 0..3

  // bijective XCD swizzle (gridDim.x % 8 == 0)
  const int nwg = gridDim.x;
  const int cpx = nwg >> 3;
  const int orig = blockIdx.x;
  const int swz = (orig & 7) * cpx + (orig >> 3);
  const int bx = swz % nbx;
  const int by = swz / nbx;
  const int m0 = by * 256, n0 = bx * 256;

  // staging source (pre-swizzled octet so linear LDS dest = swizzled layout)
  const int tr  = t >> 3;
  const int to8 = ((t & 7) ^ (tr & 7)) << 3;
  const int t8  = t << 3;
  const u16* pA0 = A  + (size_t)(m0 + tr) * K + to8;
  const u16* pB0 = Bm + (size_t)(n0 + tr) * K + to8;

  // ds_read offsets (elements), granule g=kk*4+hi XORed with row&7 (R2 exact)
  const int lr = lane & 15, hi = lane >> 4;
  const int sx = lr & 7;
  const int aK0 = ((wm * 128 + lr) << 6) + (((0 + hi) ^ sx) << 3);
  const int aK1 = ((wm * 128 + lr) << 6) + (((4 + hi) ^ sx) << 3);
  const int bK0 = 16384 + ((wn * 64 + lr) << 6) + (((0 + hi) ^ sx) << 3);
  const int bK1 = 16384 + ((wn * 64 + lr) << 6) + (((4 + hi) ^ sx) << 3);

  f32x4 acc[8][4] = {};
  short8 a[4][2], b[4][2];   // a: lo then hi (reused); b: lo AND hi live

  auto STG = [&](int kti, int isB, int h) {
    if (kti < NK) {
      const u16* g = (isB ? pB0 : pA0) + (size_t)(h * 128) * K + kti * 64;
      u16* l = &smem[((kti & 1) << 15) + (isB << 14) + (h << 13) + t8];
      async16(g, l);
      async16(g + (size_t)64 * K, l + 4096);
    }
  };

#define MFMA4x2(BN0, ACCM, ACCN)                                              \
  _Pragma("unroll")                                                           \
  for (int fm = 0; fm < 4; ++fm) {                                            \
    _Pragma("unroll")                                                         \
    for (int fn = 0; fn < 2; ++fn) {                                          \
      acc[(ACCM) + fm][(ACCN) + fn] = __builtin_amdgcn_mfma_f32_16x16x32_bf16(\
          a[fm][0], b[(BN0) + fn][0], acc[(ACCM) + fm][(ACCN) + fn], 0, 0, 0);\
      acc[(ACCM) + fm][(ACCN) + fn] = __builtin_amdgcn_mfma_f32_16x16x32_bf16(\
          a[fm][1], b[(BN0) + fn][1], acc[(ACCM) + fm][(ACCN) + fn], 0, 0, 0);\
    }                                                                         \
  }

  // prologue: stage all of tile 0
  STG(0, 0, 0); STG(0, 0, 1); STG(0, 1, 0); STG(0, 1, 1);
  asm volatile("s_waitcnt vmcnt(0)" ::: "memory");
  BARRIER();

  for (int j = 0; j < NK; ++j) {
    const u16* sa = &smem[(j & 1) << 15];

    // ---- Phase A: a-lo + b-lo + b-hi; stage ALL of tile j+1 ----
#pragma unroll
    for (int f = 0; f < 4; ++f) {
      a[f][0] = *(const short8*)&sa[aK0 + f * 1024];
      a[f][1] = *(const short8*)&sa[aK1 + f * 1024];
    }
#pragma unroll
    for (int f = 0; f < 4; ++f) {
      b[f][0] = *(const short8*)&sa[bK0 + f * 1024];
      b[f][1] = *(const short8*)&sa[bK1 + f * 1024];
    }
    STG(j + 1, 0, 0); STG(j + 1, 0, 1); STG(j + 1, 1, 0); STG(j + 1, 1, 1);
    BARRIER();
    asm volatile("s_waitcnt lgkmcnt(0)" ::: "memory");
    __builtin_amdgcn_sched_barrier(0);
    __builtin_amdgcn_s_setprio(1);
    MFMA4x2(0, 0, 0);
    MFMA4x2(2, 0, 2);
    __builtin_amdgcn_s_setprio(0);
    BARRIER();

    // ---- Phase B: a-hi (overwrites a) ----
#pragma unroll
    for (int f = 0; f < 4; ++f) {
      a[f][0] = *(const short8*)&sa[aK0 + (4 + f) * 1024];
      a[f][1] = *(const short8*)&sa[aK1 + (4 + f) * 1024];
    }
    BARRIER();
    asm volatile("s_waitcnt lgkmcnt(0)" ::: "memory");
    __builtin_amdgcn_sched_barrier(0);
    __builtin_amdgcn_s_setprio(1);
    MFMA4x2(2, 4, 2);
    MFMA4x2(0, 4, 0);
    __builtin_amdgcn_s_setprio(0);
    asm volatile("s_waitcnt vmcnt(0)" ::: "memory");
    BARRIER();
  }

  // epilogue: C/D layout col=lane&15, row=(lane>>4)*4+j  [m89/m91]
  const int erow = hi * 4;
#pragma unroll
  for (int fm = 0; fm < 8; ++fm) {
#pragma unroll
    for (int fn = 0; fn < 4; ++fn) {
      const int cg = n0 + wn * 64 + fn * 16 + lr;
      const float bb = bias[cg];
      const int rbase = m0 + wm * 128 + fm * 16 + erow;
#pragma unroll
      for (int jr = 0; jr < 4; ++jr) {
        const float val = acc[fm][fn][jr] + bb;
        if (OUT_BF16)
          ((u16*)Cout)[(size_t)(rbase + jr) * N + cg] = f2bf(val);
        else
          ((float*)Cout)[(size_t)(rbase + jr) * N + cg] = val;
      }
    }
  }
#undef MFMA4x2
}

// ---------------- token-0 attention, per (b,h), in-place on V ----------------
__global__ __launch_bounds__(64) void attn0_kernel(u16* __restrict__ V) {
  const int b = blockIdx.x, h = blockIdx.y;
  __shared__ __align__(16) u16 vt[NTOK * 64];
  __shared__ float pb[64];
  const int t = threadIdx.x;
  u16* base = V + (size_t)b * NTOK * CDIM + h * 64;
  for (int idx = t; idx < NTOK * 8; idx += 64) {
    const int m = idx >> 3, g = (idx & 7) * 8;
    *reinterpret_cast<uint4*>(&vt[m * 64 + g]) =
        *reinterpret_cast<const uint4*>(base + (size_t)m * CDIM + g);
  }
  __syncthreads();
  const float qd = bf2f(vt[t]);
  float s_own = -1e30f;
  for (int m = 0; m < NTOK; m++) {
    float p = qd * bf2f(vt[m * 64 + t]);
#pragma unroll
    for (int off = 32; off; off >>= 1) p += __shfl_xor(p, off);
    if (t == m) s_own = p * 0.125f;
  }
  float mx = s_own;
#pragma unroll
  for (int off = 32; off; off >>= 1) mx = fmaxf(mx, __shfl_xor(mx, off));
  const float e = (t < NTOK) ? __expf(s_own - mx) : 0.f;
  float Z = e;
#pragma unroll
  for (int off = 32; off; off >>= 1) Z += __shfl_xor(Z, off);
  pb[t] = e / Z;
  __syncthreads();
  float acc = 0.f;
  for (int m = 0; m < NTOK; m++) acc += pb[m] * bf2f(vt[m * 64 + t]);
  base[t] = f2bf(acc);
}

// ---------------- launch ----------------
extern "C" void kernel_launch(void* const* d_in, const int* in_sizes, int n_in,
                              void* d_out, int out_size, void* d_ws, size_t ws_size,
                              hipStream_t stream) {
  const float* x   = (const float*)d_in[0];
  const float* pos = (const float*)d_in[1];
  const float* Wv  = (const float*)d_in[2];
  const float* bv  = (const float*)d_in[3];
  const float* Wc  = (const float*)d_in[4];
  const float* bc  = (const float*)d_in[5];
  float* out = (float*)d_out;

  u16* T   = (u16*)d_ws;                        // [12800][2048] bf16
  u16* V   = T   + (size_t)MROWS * CDIM;        // [12800][2048] bf16
  u16* WvB = V   + (size_t)MROWS * CDIM;        // [2048][2048]  bf16
  u16* WcB = WvB + (size_t)CDIM * CDIM;         // [1024][2048]  bf16

  {
    int n4a = CDIM * CDIM / 4;                  // 1048576
    int n4b = ODIM * CDIM / 4;                  // 524288
    int nCvt = (n4a + n4b + 255) / 256;         // 6144
    cvt_prep_kernel<<<nCvt + BATCH * 32, 256, 0, stream>>>(
        Wv, WvB, n4a, Wc, WcB, n4b, x, pos, T, nCvt);
  }

  // GEMM1: [12800,2048]x[2048,2048]^T -> V ; grid 400 (%8==0)
  gemm256<1><<<(MROWS / 256) * (CDIM / 256), 512, 0, stream>>>(
      T, WvB, bv, V, MROWS, CDIM, CDIM, CDIM / 256);

  attn0_kernel<<<dim3(BATCH, NHEADS), 64, 0, stream>>>(V);

  // GEMM2: [12800,2048]x[1024,2048]^T -> out ; grid 200 (%8==0)
  gemm256<0><<<(MROWS / 256) * (ODIM / 256), 512, 0, stream>>>(
      V, WcB, bc, out, MROWS, ODIM, CDIM, ODIM / 256);
}